// Round 1
// baseline (1082.935 us; speedup 1.0000x reference)
//
#include <hip/hip_runtime.h>

// CTC loss forward, B=256, T=1024, C=256, L=128, S=257, blank=255.
// One wave (64 lanes) per batch element. Lane i owns states 4i..4i+3;
// lane 63 additionally owns state 256. All math in log2 domain.

#define B_DIM 256
#define T_DIM 1024
#define C_DIM 256
#define L_DIM 128
#define NEGF  (-1e30f)
#define EPSF  (1e-7f)
#define CEPSF (256.0f * 1e-7f)   // C * eps added to the row sum
#define LN2F  (0.6931471805599453f)

__device__ __forceinline__ float wave_sum64(float v) {
    #pragma unroll
    for (int m = 1; m < 64; m <<= 1) v += __shfl_xor(v, m, 64);
    return v;
}

// log2-domain logsumexp of 2 / 3 values
__device__ __forceinline__ float lse2(float a, float b) {
    float hi = fmaxf(a, b);
    float lo = fminf(a, b);
    return hi + log2f(1.0f + exp2f(lo - hi));
}
__device__ __forceinline__ float lse3(float a, float b, float c) {
    float hi  = fmaxf(fmaxf(a, b), c);                       // max3
    float lo  = fminf(fminf(a, b), c);                       // min3
    float mid = fmaxf(fminf(a, b), fminf(fmaxf(a, b), c));   // med3
    return hi + log2f(1.0f + exp2f(mid - hi) + exp2f(lo - hi));
}

__global__ __launch_bounds__(64) void ctc_fwd_kernel(
        const int* __restrict__ yt,     // [B, L] int32 labels
        const float* __restrict__ yp,   // [B, T, C] probs
        float* __restrict__ out)        // [B, 1] loss
{
    __shared__ __align__(16) float rbA[C_DIM];   // row buffers (double, by row parity)
    __shared__ __align__(16) float rbB[C_DIM];

    const int b    = blockIdx.x;
    const int lane = threadIdx.x;     // 0..63

    const float4* rowbase = (const float4*)(yp + (size_t)b * T_DIM * C_DIM);
    // row r, this lane's 4 classes: rowbase[r*64 + lane]

    // labels for this lane's odd states: s=4i+1 -> label 2i, s=4i+3 -> label 2i+1
    const int* lab = yt + b * L_DIM;
    const int lab1 = lab[2 * lane];
    const int lab3 = lab[2 * lane + 1];
    const int labm = (lane == 0) ? -1 : lab[2 * lane - 1];
    const bool skip1 = (lab1 != labm);    // for lane 0 irrelevant (a3 = NEG anyway)
    const bool skip3 = (lab3 != lab1);

    // ---- register ring of prefetched rows: slot(u) = u & 7 ----
    float4 ring[8];
    float4 p0 = rowbase[lane];                           // row 0
    #pragma unroll
    for (int u = 1; u <= 8; ++u) ring[u & 7] = rowbase[u * 64 + lane];

    // lp computation for a row held in pv; rb must be the buffer for this row's parity
    // returns lpB (blank), lp1, lp3 in log2 domain
    #define COMPUTE_LP(pv, rb, lpB_, lp1_, lp3_)                         \
        do {                                                             \
            *(float4*)&(rb)[lane * 4] = (pv);                            \
            float tot_ = wave_sum64((pv).x + (pv).y + (pv).z + (pv).w);  \
            float pBl_ = __shfl((pv).w, 63, 64);                         \
            float g1_  = (rb)[lab1];                                     \
            float g3_  = (rb)[lab3];                                     \
            float d_   = log2f(tot_ + CEPSF);                            \
            (lpB_) = log2f(pBl_ + EPSF) - d_;                            \
            (lp1_) = log2f(g1_ + EPSF) - d_;                             \
            (lp3_) = log2f(g3_ + EPSF) - d_;                             \
        } while (0)

    // ---- t = 0: init ----
    float lpB, lp1, lp3;        // lp for the step the DP is about to do
    float lpBn, lp1n, lp3n;     // lp one step ahead
    COMPUTE_LP(p0, rbA, lpB, lp1, lp3);   // row 0 (parity 0 -> rbA)

    float a0 = (lane == 0) ? lpB : NEGF;   // state 0 (blank)
    float a1 = (lane == 0) ? lp1 : NEGF;   // state 1 (label 0)
    float a2 = NEGF, a3 = NEGF, a4 = NEGF; // a4 only meaningful on lane 63 (state 256)

    // prolog: lp for row 1 (-> lp cur at loop entry) and row 2 (-> lp next)
    {
        float4 pv = ring[1];
        COMPUTE_LP(pv, rbB, lpB, lp1, lp3);        // row 1, parity 1 -> rbB
    }
    {
        float4 pv = ring[2];
        COMPUTE_LP(pv, rbA, lpBn, lp1n, lp3n);     // row 2, parity 0 -> rbA
    }

    // ---- main loop: t = 1 .. T-1 ----
    for (int t0 = 1; t0 < T_DIM; t0 += 8) {
        #pragma unroll
        for (int k = 0; k < 8; ++k) {
            const int t = t0 + k;
            if (t < T_DIM) {
                // DP step t (uses lpB/lp1/lp3 == lp of row t)
                float prev = __shfl_up(a3, 1, 64);      // alpha[4i-1] from lane i-1
                if (lane == 0) prev = NEGF;
                float n0 = lse2(a0, prev) + lpB;                          // even (blank)
                float n1 = lse3(a1, a0, skip1 ? prev : NEGF) + lp1;       // odd
                float n2 = lse2(a2, a1) + lpB;                            // even (blank)
                float n3 = lse3(a3, a2, skip3 ? a1 : NEGF) + lp3;         // odd
                float n4 = lse2(a4, a3) + lpB;                            // state 256 (lane 63)
                a0 = n0; a1 = n1; a2 = n2; a3 = n3; a4 = n4;

                // prefetch row t+8 into slot t&7 (freed 2 iters ago)
                if (t + 8 < T_DIM) ring[t & 7] = rowbase[(t + 8) * 64 + lane];

                // shift lp pipeline; compute lp for row t+2
                lpB = lpBn; lp1 = lp1n; lp3 = lp3n;
                if (t + 2 < T_DIM) {
                    float4 pv = ring[(t + 2) & 7];
                    if ((t + 2) & 1) {
                        COMPUTE_LP(pv, rbB, lpBn, lp1n, lp3n);
                    } else {
                        COMPUTE_LP(pv, rbA, lpBn, lp1n, lp3n);
                    }
                }
            }
        }
    }

    // loss = -logaddexp(alpha[S-1], alpha[S-2]) ; states 256 (a4) and 255 (a3) on lane 63
    if (lane == 63) {
        float M = fmaxf(a3, a4);
        float l2 = M + log2f(exp2f(a3 - M) + exp2f(a4 - M));
        out[b] = -l2 * LN2F;
    }
}

extern "C" void kernel_launch(void* const* d_in, const int* in_sizes, int n_in,
                              void* d_out, int out_size, void* d_ws, size_t ws_size,
                              hipStream_t stream) {
    const int*   yt = (const int*)d_in[0];     // y_true [256,128] int32
    const float* yp = (const float*)d_in[1];   // y_pred [256,1024,256] f32
    float* out = (float*)d_out;                // [256,1] f32
    (void)in_sizes; (void)n_in; (void)out_size; (void)d_ws; (void)ws_size;
    ctc_fwd_kernel<<<dim3(B_DIM), dim3(64), 0, stream>>>(yt, yp, out);
}

// Round 2
// 499.985 us; speedup vs baseline: 2.1659x; 2.1659x over previous
//
#include <hip/hip_runtime.h>

// CTC loss forward, B=256, T=1024, C=256, L=128, S=257, blank=255.
// Pass 1 (throughput): per-row invsum + max -> s_row = invsum*2^-M, M.
// Pass 2 (latency): one wave per batch element, linear-domain DP with
// per-row pre-normalization + periodic measured power-of-2 rescale.

#define B_DIM 256
#define T_DIM 1024
#define C_DIM 256
#define L_DIM 128
#define EPSF  (1e-7f)
#define CEPSF (256.0f * 1e-7f)
#define LN2F  (0.6931471805599453f)

// ---------------- pass 1: row stats ----------------
__global__ __launch_bounds__(256) void row_stats_kernel(const float* __restrict__ yp,
                                                        float2* __restrict__ sm) {
    const int row  = (blockIdx.x << 2) + (threadIdx.x >> 6);
    const int lane = threadIdx.x & 63;
    const float4* rb = (const float4*)(yp + (size_t)row * C_DIM);
    float4 v = rb[lane];
    float e0 = v.x + EPSF, e1 = v.y + EPSF, e2 = v.z + EPSF, e3 = v.w + EPSF;
    float s  = v.x + v.y + v.z + v.w;
    float mx = fmaxf(fmaxf(e0, e1), fmaxf(e2, e3));
    #pragma unroll
    for (int d = 1; d < 64; d <<= 1) {
        s  += __shfl_xor(s, d, 64);
        mx  = fmaxf(mx, __shfl_xor(mx, d, 64));
    }
    if (lane == 0) {
        float invsum = 1.0f / (s + CEPSF);
        float tm = mx * invsum;                      // max normalized prob, in (0,1]
        int   M  = (__float_as_int(tm) >> 23) - 127; // ilogb(tm), <= 0
        float srow = invsum * __int_as_float((127 - M) << 23);  // exact 2^-M scale
        sm[row] = make_float2(srow, (float)M);
    }
}

// ---------------- pass 2: DP ----------------
__global__ __launch_bounds__(64) void ctc_dp_kernel(const int* __restrict__ yt,
                                                    const float* __restrict__ yp,
                                                    const float2* __restrict__ sm,
                                                    float* __restrict__ out)
{
    const int b = blockIdx.x, lane = threadIdx.x;
    const float* base = yp + (size_t)b * (T_DIM * C_DIM);
    const int* lab = yt + b * L_DIM;
    const int lab1 = lab[2 * lane];
    const int lab3 = lab[2 * lane + 1];
    const int labm = (lane == 0) ? -1 : lab[2 * lane - 1];
    const float sk1 = (lab1 != labm) ? 1.0f : 0.0f;
    const float sk3 = (lab3 != lab1) ? 1.0f : 0.0f;
    const float* p1p = base + lab1;
    const float* p3p = base + lab3;
    const float* pBp = base + (C_DIM - 1);
    const float2* smp = sm + b * T_DIM;
    const int  bpaddr = ((lane - 1) & 63) << 2;
    const bool l0 = (lane == 0);

    // 16-row register prefetch ring
    float r1[16], r3[16], rB[16];
    float2 rs[16];
#pragma unroll
    for (int u = 0; u < 16; ++u) {
        r1[u] = p1p[(size_t)u * C_DIM];
        r3[u] = p3p[(size_t)u * C_DIM];
        rB[u] = pBp[(size_t)u * C_DIM];
        rs[u] = smp[u];
    }

    float Mtot = 0.0f, Rtot = 0.0f;
    float c1, c3, cB, n1l, n3l, nB;
    float a0, a1, a2 = 0.0f, a3 = 0.0f, a4 = 0.0f;

#define LPL(S, o1, o3, oB) do {                 \
        float s_ = rs[S].x; Mtot += rs[S].y;    \
        (o1) = (r1[S] + EPSF) * s_;             \
        (o3) = (r3[S] + EPSF) * s_;             \
        (oB) = (rB[S] + EPSF) * s_; } while (0)

    { float i1, i3, iB; LPL(0, i1, i3, iB);
      a0 = l0 ? iB : 0.0f; a1 = l0 ? i1 : 0.0f; }
    LPL(1, c1, c3, cB);
    LPL(2, n1l, n3l, nB);
    int previ = __builtin_amdgcn_ds_bpermute(bpaddr, __float_as_int(a3)); // = 0

    float m = 1.0f, w = 1.0f, s1f = 1.0f, s2f = 1.0f;

    // DP step t: alphas advance with lp(t); prefetch row t+15; compute lp(t+2).
#define STEP(T_, SPF_, S2_, DOPF_, DOLP_, APPLY_) do {                     \
        float prev = l0 ? 0.0f : __int_as_float(previ);                    \
        if (APPLY_) { prev *= s1f; prev *= s2f;                            \
            a0 *= s1f; a1 *= s1f; a2 *= s1f; a3 *= s1f; a4 *= s1f;         \
            a0 *= s2f; a1 *= s2f; a2 *= s2f; a3 *= s2f; a4 *= s2f; }       \
        float x3 = (a3 + a2 + sk3 * a1) * c3;                              \
        previ = __builtin_amdgcn_ds_bpermute(bpaddr, __float_as_int(x3));  \
        float x0 = (a0 + prev) * cB;                                       \
        float x1 = (a1 + a0 + sk1 * prev) * c1;                            \
        float x2 = (a2 + a1) * cB;                                         \
        float x4 = (a4 + a3) * cB;                                         \
        a0 = x0; a1 = x1; a2 = x2; a3 = x3; a4 = x4;                       \
        if (DOPF_) { const size_t o_ = (size_t)((T_) + 15) * C_DIM;        \
            r1[SPF_] = p1p[o_]; r3[SPF_] = p3p[o_]; rB[SPF_] = pBp[o_];    \
            rs[SPF_] = smp[(T_) + 15]; }                                   \
        c1 = n1l; c3 = n3l; cB = nB;                                       \
        if (DOLP_) { LPL(S2_, n1l, n3l, nB); }                             \
    } while (0)

    // rescale-pipeline stages, one per 2 steps (2-step gap hides ds latency)
#define STAGES(K_)                                                          \
        if ((K_) == 0)  { m = fmaxf(fmaxf(a0, a1), fmaxf(fmaxf(a2, a3), a4)); \
                          w = __shfl_xor(m, 1, 64); }                       \
        if ((K_) == 2)  { m = fmaxf(m, w); w = __shfl_xor(m, 2, 64); }      \
        if ((K_) == 4)  { m = fmaxf(m, w); w = __shfl_xor(m, 4, 64); }      \
        if ((K_) == 6)  { m = fmaxf(m, w); w = __shfl_xor(m, 8, 64); }      \
        if ((K_) == 8)  { m = fmaxf(m, w); w = __shfl_xor(m, 16, 64); }     \
        if ((K_) == 10) { m = fmaxf(m, w); w = __shfl_xor(m, 32, 64); }     \
        if ((K_) == 12) { m = fmaxf(m, w);                                  \
                          int E  = (__float_as_int(m) >> 23) - 127;         \
                          int sh = 60 - E;                                  \
                          Rtot -= (float)sh;                                \
                          int sh1 = sh >> 1, sh2 = sh - sh1;                \
                          s1f = __int_as_float((sh1 + 127) << 23);          \
                          s2f = __int_as_float((sh2 + 127) << 23); }

    // peeled first chunk: t = 1..15 (no rescale yet)
#pragma unroll
    for (int k = 1; k <= 15; ++k) {
        STEP(k, (k - 1) & 15, (k + 2) & 15, 1, 1, 0);
    }

    // main chunks: t = 16 .. 1007
    for (int t0 = 16; t0 <= 992; t0 += 16) {
#pragma unroll
        for (int k = 0; k < 16; ++k) {
            STAGES(k)
            STEP(t0 + k, (k + 15) & 15, (k + 2) & 15, 1, 1, (k == 13));
        }
    }

    // last chunk: t = 1008..1023
    {
        const int t0 = 1008;
#pragma unroll
        for (int k = 0; k < 16; ++k) {
            STAGES(k)
            STEP(t0 + k, (k + 15) & 15, (k + 2) & 15, (k == 0), (k <= 13), (k == 13));
        }
    }

    if (lane == 63) {
        float v = a3 + a4;   // states 255 and 256
        out[b] = -(log2f(v) + Mtot + Rtot) * LN2F;
    }
#undef STEP
#undef STAGES
#undef LPL
}

extern "C" void kernel_launch(void* const* d_in, const int* in_sizes, int n_in,
                              void* d_out, int out_size, void* d_ws, size_t ws_size,
                              hipStream_t stream) {
    const int*   yt = (const int*)d_in[0];     // y_true [256,128] int32
    const float* yp = (const float*)d_in[1];   // y_pred [256,1024,256] f32
    float* out = (float*)d_out;                // [256,1] f32
    float2* sm = (float2*)d_ws;                // 256*1024 float2 = 2 MB scratch
    (void)in_sizes; (void)n_in; (void)out_size; (void)ws_size;
    row_stats_kernel<<<dim3((B_DIM * T_DIM) / 4), dim3(256), 0, stream>>>(yp, sm);
    ctc_dp_kernel<<<dim3(B_DIM), dim3(64), 0, stream>>>(yt, yp, sm, out);
}